// Round 5
// baseline (136.809 us; speedup 1.0000x reference)
//
#include <hip/hip_runtime.h>
#include <hip/hip_bf16.h>
#include <stdint.h>

typedef __attribute__((ext_vector_type(8))) short short8;
typedef __attribute__((ext_vector_type(4))) float f32x4;

// ---------------- ws layout (bytes) ----------------
// Xpad granules: [b(8)][cb(8)][y(66)][x(66)][slot(4)] * 16B = 17,842,176
#define XP_BYTES   17842176
#define XP_PAD     1024
#define OFF_W9     (XP_BYTES + XP_PAD)            // 17,843,200
#define W9_BYTES   (8*9*256*32*2)                 // 1,179,648
#define OFF_BIAS   (OFF_W9 + W9_BYTES)

__device__ __forceinline__ short f2bf(float f) {
  __hip_bfloat16 h = __float2bfloat16(f);
  return *reinterpret_cast<short*>(&h);
}

__device__ __forceinline__ void gl_lds16(const void* g, void* l) {
  __builtin_amdgcn_global_load_lds(
      (const __attribute__((address_space(1))) void*)g,
      (__attribute__((address_space(3))) void*)l, 16, 0, 0);
}

// Fused prep: blocks [0,256) do weight prep (one block per o); blocks
// [256, 4480) do pad+transpose. Single launch hides weights under pad.
__global__ void k_prep(const float* __restrict__ X,
                       const float* __restrict__ core1,
                       const float* __restrict__ core2,
                       const float* __restrict__ core3,
                       const float* __restrict__ convw,
                       const float* __restrict__ convb,
                       short* __restrict__ Xp,
                       short* __restrict__ W9, float* __restrict__ bias) {
  if (blockIdx.x < 256) {
    // ---------------- weights ----------------
    __shared__ float H2s[1024];   // [u(16)][j(8)][k(8)]
    __shared__ float red[256];
    const int o = blockIdx.x, c = threadIdx.x;
    const int a = o >> 6, c2 = (o >> 3) & 7, d = o & 7;
#pragma unroll
    for (int p = 0; p < 4; ++p) {
      int idx = c + (p << 8);
      int k = idx & 7, j = (idx >> 3) & 7, u = idx >> 6;
      float s = 0.f;
#pragma unroll
      for (int v = 0; v < 16; ++v)
        s += core2[(c2 * 16 + v) * 128 + u * 8 + j] * core3[d * 128 + v * 8 + k];
      H2s[idx] = s;
    }
    __syncthreads();
    const int i = c >> 6, j = (c >> 3) & 7, k = c & 7;
    float Wr[16];
#pragma unroll
    for (int r = 0; r < 16; ++r) Wr[r] = 0.f;
    for (int u = 0; u < 16; ++u) {
      float h = H2s[u * 64 + j * 8 + k];
      const float* c1 = core1 + (a * 16 + u) * 64 + i;
#pragma unroll
      for (int r = 0; r < 16; ++r) Wr[r] += c1[r * 4] * h;
    }
    const int cb = c >> 5, cl = c & 31, g = cl >> 3, pos = cl & 7;
    const int gslot = g ^ (o & 3);
#pragma unroll
    for (int t = 0; t < 9; ++t) {
      float s = 0.f;
#pragma unroll
      for (int r = 0; r < 16; ++r) s += Wr[r] * convw[r * 9 + t];
      W9[((size_t)((cb * 9 + t) * 256 + o)) * 32 + gslot * 8 + pos] = f2bf(s);
    }
    float s = 0.f;
#pragma unroll
    for (int r = 0; r < 16; ++r) s += Wr[r] * convb[r];
    red[c] = s;
    __syncthreads();
    for (int st = 128; st > 0; st >>= 1) {
      if (c < st) red[c] += red[c + st];
      __syncthreads();
    }
    if (c == 0) bias[o] = red[0];
    return;
  }
  // ---------------- pad+transpose ----------------
  const int p = blockIdx.x - 256;
  const int cb = p / 528, rem = p % 528;
  const int b = rem / 66, yp = rem % 66;
  const int t = threadIdx.x;
  const int x = t & 63, sub = t >> 6;       // sub = channel-group g (0..3)
  const size_t rowg = ((size_t)((b * 8 + cb) * 66 + yp)) * 264;
  const short8 z = (short8){0, 0, 0, 0, 0, 0, 0, 0};
  if (yp == 0 || yp == 65) {
    *(short8*)(Xp + (rowg + (size_t)(x << 2) + sub) * 8) = z;
    if (x < 2)
      *(short8*)(Xp + (rowg + (size_t)((64 + x) << 2) + sub) * 8) = z;
    return;
  }
  const int y = yp - 1, xp = x + 1;
  const int gslot = sub ^ ((xp >> 1) & 3);
  const float* src = X + ((size_t)(b * 256 + cb * 32 + sub * 8) * 64 + y) * 64 + x;
  short8 v;
#pragma unroll
  for (int k = 0; k < 8; ++k) v[k] = f2bf(src[(size_t)k * 4096]);
  *(short8*)(Xp + (rowg + (size_t)(xp << 2) + gslot) * 8) = v;
  if (x < 2)
    *(short8*)(Xp + (rowg + (size_t)((x * 65) << 2) + sub) * 8) = z;
}

// main GEMM, io=4: out[b,o,h,w] = bias[o] + sum_{c,t} K9[o,c,t]*Xpad[...]
// Block = 8 rows x 64 o x 32 x, 256 thr (4 waves), wave = 2 rows x 64 o x 32 x.
// Grid 8h x (2xh*4o) x 8b = 512 blocks = 2/CU -> 2 waves/SIMD. Each 1KB X
// fragment read feeds 6 MFMAs (io=4 reuse): LDS reads/CU ~halved vs io=2.
// X slab: 10 rows x 48 x-cols x 4 slots = 30KB, double-buffered (2 blocks/CU
// = 122.9KB). Per cb: one barrier; stage(cb+1) split in halves; af loads
// issued BEFORE each stage half so every af vmcnt-wait is counted (stage
// never drains mid-cb). 24-MFMA clusters (~116cyc) cover ds_read latency.
__global__ __launch_bounds__(256, 2) void k_gemm(
    const short* __restrict__ Xp, const short* __restrict__ W9,
    const float* __restrict__ bias, float* __restrict__ out) {
  __shared__ __align__(16) short XL[2][15360];   // 2 x 30,720 B

  const int tid  = threadIdx.x;
  const int lane = tid & 63;
  const int wv   = tid >> 6;           // 4 waves
  const int l15  = lane & 15;
  const int gl   = lane >> 4;          // k-granule 0..3
  const int hb    = blockIdx.x;        // 8 output rows / block
  const int h0p   = hb << 3;           // first padded row needed
  const int o4    = blockIdx.y & 3;
  const int xh    = blockIdx.y >> 2;
  const int oBase = o4 << 6;           // 64 out-channels / block
  const int x0    = xh << 5;           // 32 x / block
  const int xlo   = xh ? 18 : 0;       // staged x-range [xlo, xlo+48)
  const int b     = blockIdx.z;

  // LDS short-offsets for bfr reads at ip=0; ip=1 adds 512 (slot key safe:
  // (x+16)>>1 & 3 == (x>>1)&3 ^ 0 since 16>>1=8 ≡ 0 mod 4... (x+16)>>1 =
  // (x>>1)+8 -> &3 unchanged).
  int xoff[4][3];
#pragma unroll
  for (int j = 0; j < 4; ++j)
#pragma unroll
    for (int dx = 0; dx < 3; ++dx) {
      const int x = x0 + l15 + dx;
      xoff[j][dx] = ((wv << 1) + j) * 1536 + (x - xlo) * 32 +
                    ((gl ^ ((x >> 1) & 3)) << 3);
    }
  const int laneW = ((gl ^ (l15 & 3)) << 3);

  f32x4 acc[2][4][2];
#pragma unroll
  for (int rr = 0; rr < 2; ++rr)
#pragma unroll
    for (int io = 0; io < 4; ++io)
#pragma unroll
      for (int ip = 0; ip < 2; ++ip)
        acc[rr][io][ip] = (f32x4){0.f, 0.f, 0.f, 0.f};

  // stage: 10 rows x 3 chunks of 1KB (64 granules = 16 x-cols each)
#define STG(CB, BUF, QLO, QHI)                                               \
  {                                                                          \
    _Pragma("unroll 1")                                                      \
    for (int q = (QLO) + wv; q < (QHI); q += 4) {                            \
      const int row = q / 3, xc = q % 3;                                     \
      const size_t gg = (((size_t)((b << 3) + (CB)) * 66 + h0p + row) * 264  \
                         + (xlo << 2) + (xc << 6) + lane) << 3;              \
      gl_lds16(Xp + gg, &XL[BUF][q << 9]);                                   \
    }                                                                        \
  }

  STG(0, 0, 0, 30);   // prologue

  short8 af0[3][4], af1[3][4];   // af slots: dx0->af0, dx1->af1, dx2->af0
  short8 bfr[2][4];

#define AFLOAD(DST, CB, DX)                                                  \
  {                                                                          \
    _Pragma("unroll")                                                        \
    for (int dy = 0; dy < 3; ++dy)                                           \
      _Pragma("unroll")                                                      \
      for (int io = 0; io < 4; ++io)                                         \
        DST[dy][io] = *(const short8*)&W9[                                   \
            (size_t)(((CB) * 9 + dy * 3 + (DX)) * 256 + oBase + (io << 4)    \
                     + l15) * 32 + laneW];                                   \
  }

#define LOADS(BUF, DX, IP)                                                   \
  {                                                                          \
    _Pragma("unroll")                                                        \
    for (int j = 0; j < 4; ++j)                                              \
      bfr[BUF][j] = *(const short8*)&XLc[xoff[j][DX] + ((IP) << 9)];         \
  }

#define MM(AF, RB)                                                           \
  {                                                                          \
    __builtin_amdgcn_s_setprio(1);                                           \
    _Pragma("unroll")                                                        \
    for (int dy = 0; dy < 3; ++dy)                                           \
      _Pragma("unroll")                                                      \
      for (int rr = 0; rr < 2; ++rr)                                         \
        _Pragma("unroll")                                                    \
        for (int io = 0; io < 4; ++io)                                       \
          acc[rr][io][ipc] = __builtin_amdgcn_mfma_f32_16x16x32_bf16(        \
              AF[dy][io], bfr[RB][rr + dy], acc[rr][io][ipc], 0, 0, 0);      \
    __builtin_amdgcn_s_setprio(0);                                           \
  }

  for (int cb = 0; cb < 8; ++cb) {
    __syncthreads();                    // XL[cb&1] ready (staged last cb)
    const short* XLc = &XL[cb & 1][0];

    AFLOAD(af0, cb, 0);                 // af dx0 (waits become vmcnt(counted))
    __builtin_amdgcn_sched_barrier(0);
    if (cb < 7) STG(cb + 1, (cb + 1) & 1, 0, 15);   // stage half 1
    __builtin_amdgcn_sched_barrier(0);

    LOADS(0, 0, 0);
    { const int ipc = 0; LOADS(1, 0, 1); __builtin_amdgcn_sched_barrier(0); MM(af0, 0); }
    { const int ipc = 1; LOADS(0, 1, 0); __builtin_amdgcn_sched_barrier(0); MM(af0, 1); }

    AFLOAD(af1, cb, 1);                 // af dx1
    AFLOAD(af0, cb, 2);                 // af dx2 (dx0 regs dead)
    __builtin_amdgcn_sched_barrier(0);
    if (cb < 7) STG(cb + 1, (cb + 1) & 1, 15, 30);  // stage half 2
    __builtin_amdgcn_sched_barrier(0);

    { const int ipc = 0; LOADS(1, 1, 1); __builtin_amdgcn_sched_barrier(0); MM(af1, 0); }
    { const int ipc = 1; LOADS(0, 2, 0); __builtin_amdgcn_sched_barrier(0); MM(af1, 1); }
    { const int ipc = 0; LOADS(1, 2, 1); __builtin_amdgcn_sched_barrier(0); MM(af0, 0); }
    { const int ipc = 1;                 __builtin_amdgcn_sched_barrier(0); MM(af0, 1); }
  }
#undef MM
#undef LOADS
#undef AFLOAD
#undef STG

  // epilogue
#pragma unroll
  for (int rr = 0; rr < 2; ++rr) {
    const int h = (hb << 3) + (wv << 1) + rr;
#pragma unroll
    for (int io = 0; io < 4; ++io) {
#pragma unroll
      for (int r = 0; r < 4; ++r) {
        const int oG = oBase + (io << 4) + (gl << 2) + r;
        const float bv = bias[oG];
        float* op = out + (((size_t)((b << 8) + oG)) << 12) + (h << 6) + x0;
#pragma unroll
        for (int ip = 0; ip < 2; ++ip)
          op[(ip << 4) + l15] = acc[rr][io][ip][r] + bv;
      }
    }
  }
}

extern "C" void kernel_launch(void* const* d_in, const int* in_sizes, int n_in,
                              void* d_out, int out_size, void* d_ws, size_t ws_size,
                              hipStream_t stream) {
  (void)in_sizes; (void)n_in; (void)out_size; (void)ws_size;
  const float* X     = (const float*)d_in[0];
  const float* convw = (const float*)d_in[1];
  const float* convb = (const float*)d_in[2];
  const float* core1 = (const float*)d_in[3];
  const float* core2 = (const float*)d_in[4];
  const float* core3 = (const float*)d_in[5];
  float* out = (float*)d_out;
  char*  ws  = (char*)d_ws;

  short* Xp   = (short*)ws;
  short* W9   = (short*)(ws + OFF_W9);
  float* bias = (float*)(ws + OFF_BIAS);

  // fused weights+pad (no memset: k_prep writes every Xpad granule)
  k_prep<<<4480, 256, 0, stream>>>(X, core1, core2, core3, convw, convb,
                                   Xp, W9, bias);
  k_gemm<<<dim3(8, 8, 8), 256, 0, stream>>>(Xp, W9, bias, out);
}

// Round 6
// 131.718 us; speedup vs baseline: 1.0386x; 1.0386x over previous
//
#include <hip/hip_runtime.h>
#include <hip/hip_bf16.h>
#include <stdint.h>

typedef __attribute__((ext_vector_type(8))) short short8;
typedef __attribute__((ext_vector_type(4))) float f32x4;

// ---------------- ws layout (bytes) ----------------
// Xpad granules: [b(8)][cb(8)][y(66)][x(66)][slot(4)] * 16B = 17,842,176
#define XP_BYTES   17842176
#define XP_PAD     1024
#define OFF_W9     (XP_BYTES + XP_PAD)            // 17,843,200
#define W9_BYTES   (8*9*256*32*2)                 // 1,179,648
#define OFF_BIAS   (OFF_W9 + W9_BYTES)

__device__ __forceinline__ short f2bf(float f) {
  __hip_bfloat16 h = __float2bfloat16(f);
  return *reinterpret_cast<short*>(&h);
}

__device__ __forceinline__ void gl_lds16(const void* g, void* l) {
  __builtin_amdgcn_global_load_lds(
      (const __attribute__((address_space(1))) void*)g,
      (__attribute__((address_space(3))) void*)l, 16, 0, 0);
}

// Fused prep: blocks [0,256) do weight prep (one block per o); blocks
// [256, 4480) do pad+transpose, one block per (b,cb,yp) row.
// Pad writes go through LDS so the global stores are lane-consecutive
// full-sector b128 -> no partial-64B-sector RMW at TCC (the r5 version's
// 16B-scatter writes were the hidden ~25 microsec cost).
__global__ void k_prep(const float* __restrict__ X,
                       const float* __restrict__ core1,
                       const float* __restrict__ core2,
                       const float* __restrict__ core3,
                       const float* __restrict__ convw,
                       const float* __restrict__ convb,
                       short* __restrict__ Xp,
                       short* __restrict__ W9, float* __restrict__ bias) {
  if (blockIdx.x < 256) {
    // ---------------- weights ----------------
    __shared__ float H2s[1024];   // [u(16)][j(8)][k(8)]
    __shared__ float red[256];
    const int o = blockIdx.x, c = threadIdx.x;
    const int a = o >> 6, c2 = (o >> 3) & 7, d = o & 7;
#pragma unroll
    for (int p = 0; p < 4; ++p) {
      int idx = c + (p << 8);
      int k = idx & 7, j = (idx >> 3) & 7, u = idx >> 6;
      float s = 0.f;
#pragma unroll
      for (int v = 0; v < 16; ++v)
        s += core2[(c2 * 16 + v) * 128 + u * 8 + j] * core3[d * 128 + v * 8 + k];
      H2s[idx] = s;
    }
    __syncthreads();
    const int i = c >> 6, j = (c >> 3) & 7, k = c & 7;
    float Wr[16];
#pragma unroll
    for (int r = 0; r < 16; ++r) Wr[r] = 0.f;
    for (int u = 0; u < 16; ++u) {
      float h = H2s[u * 64 + j * 8 + k];
      const float* c1 = core1 + (a * 16 + u) * 64 + i;
#pragma unroll
      for (int r = 0; r < 16; ++r) Wr[r] += c1[r * 4] * h;
    }
    const int cb = c >> 5, cl = c & 31, g = cl >> 3, pos = cl & 7;
    const int gslot = g ^ (o & 3);
#pragma unroll
    for (int t = 0; t < 9; ++t) {
      float s = 0.f;
#pragma unroll
      for (int r = 0; r < 16; ++r) s += Wr[r] * convw[r * 9 + t];
      W9[((size_t)((cb * 9 + t) * 256 + o)) * 32 + gslot * 8 + pos] = f2bf(s);
    }
    float s = 0.f;
#pragma unroll
    for (int r = 0; r < 16; ++r) s += Wr[r] * convb[r];
    red[c] = s;
    __syncthreads();
    for (int st = 128; st > 0; st >>= 1) {
      if (c < st) red[c] += red[c + st];
      __syncthreads();
    }
    if (c == 0) bias[o] = red[0];
    return;
  }
  // ---------------- pad+transpose (LDS-staged row) ----------------
  const int p = blockIdx.x - 256;
  const int cb = p / 528, rem = p % 528;
  const int b = rem / 66, yp = rem % 66;
  const int t = threadIdx.x;
  short* rowp = Xp + ((size_t)((b * 8 + cb) * 66 + yp)) * 264 * 8;
  const short8 z = (short8){0, 0, 0, 0, 0, 0, 0, 0};
  if (yp == 0 || yp == 65) {
    // all-zero row: 264 granules, contiguous stores
    *(short8*)(rowp + t * 8) = z;
    if (t < 8) *(short8*)(rowp + ((256 + t) * 8)) = z;
    return;
  }
  __shared__ __align__(16) short Ls[264 * 8];   // one padded row, 4224 B
  // zero-init (covers xp=0 and xp=65 border granules)
  *(short8*)&Ls[t * 8] = z;
  if (t < 8) *(short8*)&Ls[(256 + t) * 8] = z;
  __syncthreads();
  const int x = t & 63, sub = t >> 6, xp = x + 1, y = yp - 1;
  const int gslot = sub ^ ((xp >> 1) & 3);
  const float* src = X + ((size_t)(b * 256 + cb * 32 + sub * 8) * 64 + y) * 64 + x;
  short8 v;
#pragma unroll
  for (int k = 0; k < 8; ++k) v[k] = f2bf(src[(size_t)k * 4096]);
  *(short8*)&Ls[(xp * 4 + gslot) * 8] = v;
  __syncthreads();
  // contiguous write-out: 264 b128, lane-consecutive -> full 64B sectors
  *(short8*)(rowp + t * 8) = *(const short8*)&Ls[t * 8];
  if (t < 8) *(short8*)(rowp + (256 + t) * 8) = *(const short8*)&Ls[(256 + t) * 8];
}

// main GEMM (r4 version, measured ~41.5us): out = bias + sum_{c,t} K9*Xpad
// Block = 16 rows x 32 o, 512 threads (8 waves), wave = 2 rows x 32 o.
// Grid (4,8,8) = 256 blocks = 1/CU -> 2 waves/SIMD. X-only LDS double buffer.
// One barrier per cb; stage(cb+1) issued after it, drained at next barrier.
// Inner loop: 12 steps (3 dx x 4 ip), register-double-buffered bfr prefetch
// overlapped with 12-MFMA setprio clusters.
__global__ __launch_bounds__(512, 1) void k_gemm(
    const short* __restrict__ Xp, const short* __restrict__ W9,
    const float* __restrict__ bias, float* __restrict__ out) {
  __shared__ __align__(16) short XL[2][38400];  // 2 x 76.8 KB = 153.6 KB

  const int tid  = threadIdx.x;
  const int lane = tid & 63;
  const int wv   = tid >> 6;           // 8 waves
  const int l15  = lane & 15;
  const int gl   = lane >> 4;          // k-granule 0..3
  const int h0    = blockIdx.x << 4;   // 16 output rows / block
  const int oBase = blockIdx.y << 5;   // 32 out-channels / block
  const int b     = blockIdx.z;
  const int r0    = wv << 1;           // wave's local output-row base (0..14)

  // precomputed LDS short-offsets: xoff[xr][dx] for row r0+xr, x=l15+dx (+16ip)
  int xoff[4][3];
#pragma unroll
  for (int xr = 0; xr < 4; ++xr)
#pragma unroll
    for (int dx = 0; dx < 3; ++dx)
      xoff[xr][dx] = ((r0 + xr) * 66 + l15 + dx) * 32 +
                     ((gl ^ (((l15 + dx) >> 1) & 3)) << 3);

  // af lane offset (shorts) into W9: per (cb,t,io) add cb*73728+t*8192+io*512
  const int laneW = (oBase + l15) * 32 + ((gl ^ (l15 & 3)) << 3);

  f32x4 acc[2][2][4];
#pragma unroll
  for (int rr = 0; rr < 2; ++rr)
#pragma unroll
    for (int io = 0; io < 2; ++io)
#pragma unroll
      for (int ip = 0; ip < 4; ++ip)
        acc[rr][io][ip] = (f32x4){0.f, 0.f, 0.f, 0.f};

  // stage helper: 18 padded rows x 264 granules = 76,032 B -> 75 x 1KB chunks
  // (chunk 74 over-reads 768 B of the next slab: in-bounds, unused)
#define STAGE(CB, BUF)                                                     \
  {                                                                        \
    const size_t xb = ((size_t)(((b << 3) + (CB)) * 66 + h0) * 66) << 5;   \
    _Pragma("unroll 1")                                                    \
    for (int q = wv; q < 75; q += 8)                                       \
      gl_lds16(Xp + xb + (q << 9) + (lane << 3), &XL[BUF][q << 9]);        \
  }

  STAGE(0, 0);   // prologue

  for (int cb = 0; cb < 8; ++cb) {
    // af preload: 18 global b128, issued BEFORE the barrier so the barrier's
    // drain covers them (no vmcnt wait can ever drain the next stage queue)
    const short* Wc = W9 + cb * 73728 + laneW;
    short8 af[9][2];
#pragma unroll
    for (int t = 0; t < 9; ++t)
#pragma unroll
      for (int io = 0; io < 2; ++io)
        af[t][io] = *(const short8*)&Wc[t * 8192 + (io << 9)];
    __builtin_amdgcn_sched_barrier(0);

    __syncthreads();   // drains stage(cb) (+af); XL[cb&1] ready

    if (cb < 7) STAGE(cb + 1, (cb + 1) & 1);
    __builtin_amdgcn_sched_barrier(0);

    const short* XLc = &XL[cb & 1][0];
    short8 bfr[2][4];  // [regbuf][xr], static-indexed (full unroll)

#define LOADS(BUF, DX, IP)                                                 \
  {                                                                        \
    _Pragma("unroll")                                                      \
    for (int xr = 0; xr < 4; ++xr)                                         \
      bfr[BUF][xr] = *(const short8*)&XLc[xoff[xr][DX] + ((IP) << 9)];     \
  }

    LOADS(0, 0, 0);    // step-0 fragments
#pragma unroll
    for (int s = 0; s < 12; ++s) {
      const int dx = s >> 2, ip = s & 3, buf = s & 1;
      if (s < 11) LOADS(buf ^ 1, (s + 1) >> 2, (s + 1) & 3);
      __builtin_amdgcn_sched_barrier(0);   // reads issued before MFMA cluster
      __builtin_amdgcn_s_setprio(1);
#pragma unroll
      for (int dy = 0; dy < 3; ++dy) {
        const int t = dy * 3 + dx;
#pragma unroll
        for (int io = 0; io < 2; ++io) {
          acc[0][io][ip] = __builtin_amdgcn_mfma_f32_16x16x32_bf16(
              af[t][io], bfr[buf][dy], acc[0][io][ip], 0, 0, 0);
          acc[1][io][ip] = __builtin_amdgcn_mfma_f32_16x16x32_bf16(
              af[t][io], bfr[buf][dy + 1], acc[1][io][ip], 0, 0, 0);
        }
      }
      __builtin_amdgcn_s_setprio(0);
    }
#undef LOADS
  }
#undef STAGE

  // epilogue
#pragma unroll
  for (int rr = 0; rr < 2; ++rr) {
    const int h = h0 + r0 + rr;
#pragma unroll
    for (int io = 0; io < 2; ++io) {
#pragma unroll
      for (int r = 0; r < 4; ++r) {
        const int oG = oBase + (io << 4) + (gl << 2) + r;
        const float bv = bias[oG];
        float* op = out + (((size_t)((b << 8) + oG)) << 12) + (h << 6);
#pragma unroll
        for (int ip = 0; ip < 4; ++ip)
          op[(ip << 4) + l15] = acc[rr][io][ip][r] + bv;
      }
    }
  }
}

extern "C" void kernel_launch(void* const* d_in, const int* in_sizes, int n_in,
                              void* d_out, int out_size, void* d_ws, size_t ws_size,
                              hipStream_t stream) {
  (void)in_sizes; (void)n_in; (void)out_size; (void)ws_size;
  const float* X     = (const float*)d_in[0];
  const float* convw = (const float*)d_in[1];
  const float* convb = (const float*)d_in[2];
  const float* core1 = (const float*)d_in[3];
  const float* core2 = (const float*)d_in[4];
  const float* core3 = (const float*)d_in[5];
  float* out = (float*)d_out;
  char*  ws  = (char*)d_ws;

  short* Xp   = (short*)ws;
  short* W9   = (short*)(ws + OFF_W9);
  float* bias = (float*)(ws + OFF_BIAS);

  // fused weights+pad (no memset: k_prep writes every Xpad granule)
  k_prep<<<4480, 256, 0, stream>>>(X, core1, core2, core3, convw, convb,
                                   Xp, W9, bias);
  k_gemm<<<dim3(4, 8, 8), 512, 0, stream>>>(Xp, W9, bias, out);
}